// Round 4
// baseline (1369.121 us; speedup 1.0000x reference)
//
#include <hip/hip_runtime.h>
#include <hip/hip_bf16.h>
#include <math.h>

#define NB 64
#define NS 1024
#define NH 1024
#define NE 1024
#define NA 1024

#define BM 128
#define BN 128
#define BK 64

typedef __attribute__((ext_vector_type(8))) short bf16x8;
typedef __attribute__((ext_vector_type(4))) float f32x4;

__device__ __forceinline__ unsigned short f2bf(float x) {
    __hip_bfloat16 h = __float2bfloat16(x);
    return *reinterpret_cast<unsigned short*>(&h);
}
__device__ __forceinline__ float bf2f(unsigned short u) {
    __hip_bfloat16 h = *reinterpret_cast<__hip_bfloat16*>(&u);
    return __bfloat162float(h);
}
__device__ __forceinline__ float tanh_fast(float x) {
    float ax = fabsf(x);
    float e = __expf(-2.f * ax);
    float r = (1.f - e) / (1.f + e);
    return x < 0.f ? -r : r;
}
// XOR-swizzled byte offset into a [row][64 bf16] LDS tile (row stride 128 B).
// Spreads 16-row column reads across 8 16B slots -> 2-way bank alias (free).
__device__ __forceinline__ int swz(int row, int colBf16) {
    return (row * 128 + colBf16 * 2) ^ ((row & 7) << 4);
}

// ---------------- kernel 0: UaT hi/lo split:  UaT[a][e] = split(Ua[e][a]) ----------------
__global__ __launch_bounds__(256) void split_uat_kernel(
    const float* __restrict__ Ua,
    unsigned short* __restrict__ uatHi, unsigned short* __restrict__ uatLo)
{
    __shared__ float tile[32][33];
    const int e0 = blockIdx.x * 32, a0 = blockIdx.y * 32;
    const int tx = threadIdx.x & 31, ty = threadIdx.x >> 5;  // ty 0..7
#pragma unroll
    for (int j = 0; j < 4; ++j)
        tile[ty + j * 8][tx] = Ua[(size_t)(e0 + ty + j * 8) * NA + a0 + tx];
    __syncthreads();
#pragma unroll
    for (int j = 0; j < 4; ++j) {
        const int a = a0 + ty + j * 8;
        const float x = tile[tx][ty + j * 8];
        const unsigned short h = f2bf(x);
        const unsigned short l = f2bf(x - bf2f(h));
        uatHi[(size_t)a * NE + e0 + tx] = h;
        uatLo[(size_t)a * NE + e0 + tx] = l;
    }
}

// ---------------- kernel 1: k_dec = dec @ W_a  -> [B, A] (fp32 vector) ----------------
__global__ __launch_bounds__(256) void kdec_kernel(
    const float* __restrict__ dec, const float* __restrict__ Wa,
    float* __restrict__ kdec)
{
    __shared__ float dls[NH];
    const int b = blockIdx.x;
    const int a = blockIdx.y * 256 + threadIdx.x;
    for (int i = threadIdx.x; i < NH; i += 256) dls[i] = dec[b * NH + i];
    __syncthreads();
    float acc = 0.f;
#pragma unroll 8
    for (int h = 0; h < NH; ++h) acc += dls[h] * Wa[(size_t)h * NA + a];
    kdec[b * NA + a] = acc;
}

// ------- kernel 2: fused scores via split-bf16 MFMA -------
// scores[b,s] = sum_a tanh(kdec[b,a] + (enc@Ua)[b,s,a]) * va[a]
__global__ __launch_bounds__(256, 2) void scores_kernel(
    const float* __restrict__ enc,
    const unsigned short* __restrict__ uatHi, const unsigned short* __restrict__ uatLo,
    const float* __restrict__ kdec, const float* __restrict__ va,
    float* __restrict__ scores)
{
    __shared__ __align__(16) char aHi[BM * BK * 2];  // 16 KB each
    __shared__ __align__(16) char aLo[BM * BK * 2];
    __shared__ __align__(16) char bHi[BN * BK * 2];
    __shared__ __align__(16) char bLo[BN * BK * 2];
    __shared__ float scLds[2][BM];

    const int t    = threadIdx.x;
    const int b    = blockIdx.y;
    const int s0   = blockIdx.x * BM;
    const int lane = t & 63;
    const int wid  = t >> 6;
    const int wr   = wid >> 1;          // wave row 0..1 (64 s-rows each)
    const int wc   = wid & 1;           // wave col 0..1 (64 a-cols each)
    const int lr   = lane & 15;         // fragment row/col
    const int lk   = (lane >> 4) * 8;   // fragment k offset

    const float* encB = enc + ((size_t)b * NS + s0) * NE;

    float scp[4][4];                    // per-lane partial row sums
#pragma unroll
    for (int i = 0; i < 4; ++i)
#pragma unroll
        for (int r = 0; r < 4; ++r) scp[i][r] = 0.f;

    for (int ac = 0; ac < NA / BN; ++ac) {
        const int a0 = ac * BN;
        f32x4 acc[4][4];
#pragma unroll
        for (int fi = 0; fi < 4; ++fi)
#pragma unroll
            for (int fj = 0; fj < 4; ++fj) acc[fi][fj] = (f32x4){0.f, 0.f, 0.f, 0.f};

        for (int e0 = 0; e0 < NE; e0 += BK) {
            __syncthreads();  // previous iter's frag reads done before overwrite
            // ---- stage A: enc fp32 -> bf16 hi/lo, swizzled ----
#pragma unroll
            for (int it = 0; it < 8; ++it) {
                const int flat = t + it * 256;       // 0..2047
                const int row  = flat >> 4;          // 0..127
                const int c4   = (flat & 15) * 4;    // col (floats)
                const float4 v = *reinterpret_cast<const float4*>(
                    encB + (size_t)row * NE + e0 + c4);
                ushort4 h, l;
                h.x = f2bf(v.x); l.x = f2bf(v.x - bf2f(h.x));
                h.y = f2bf(v.y); l.y = f2bf(v.y - bf2f(h.y));
                h.z = f2bf(v.z); l.z = f2bf(v.z - bf2f(h.z));
                h.w = f2bf(v.w); l.w = f2bf(v.w - bf2f(h.w));
                *reinterpret_cast<ushort4*>(aHi + swz(row, c4)) = h;
                *reinterpret_cast<ushort4*>(aLo + swz(row, c4)) = l;
            }
            // ---- stage B: pre-split UaT bf16 copies, swizzled ----
#pragma unroll
            for (int it = 0; it < 4; ++it) {
                const int flat = t + it * 256;       // 0..1023
                const int row  = flat >> 3;          // 0..127 (a)
                const int c8   = (flat & 7) * 8;     // col (bf16)
                const size_t g = (size_t)(a0 + row) * NE + e0 + c8;
                *reinterpret_cast<int4*>(bHi + swz(row, c8)) =
                    *reinterpret_cast<const int4*>(uatHi + g);
                *reinterpret_cast<int4*>(bLo + swz(row, c8)) =
                    *reinterpret_cast<const int4*>(uatLo + g);
            }
            __syncthreads();

#pragma unroll
            for (int ks = 0; ks < BK; ks += 32) {
                bf16x8 aH[4], aL[4], bH[4], bL[4];
#pragma unroll
                for (int f = 0; f < 4; ++f) {
                    aH[f] = *reinterpret_cast<const bf16x8*>(aHi + swz(wr * 64 + f * 16 + lr, ks + lk));
                    aL[f] = *reinterpret_cast<const bf16x8*>(aLo + swz(wr * 64 + f * 16 + lr, ks + lk));
                    bH[f] = *reinterpret_cast<const bf16x8*>(bHi + swz(wc * 64 + f * 16 + lr, ks + lk));
                    bL[f] = *reinterpret_cast<const bf16x8*>(bLo + swz(wc * 64 + f * 16 + lr, ks + lk));
                }
#pragma unroll
                for (int fi = 0; fi < 4; ++fi)
#pragma unroll
                    for (int fj = 0; fj < 4; ++fj) {
                        acc[fi][fj] = __builtin_amdgcn_mfma_f32_16x16x32_bf16(aH[fi], bH[fj], acc[fi][fj], 0, 0, 0);
                        acc[fi][fj] = __builtin_amdgcn_mfma_f32_16x16x32_bf16(aH[fi], bL[fj], acc[fi][fj], 0, 0, 0);
                        acc[fi][fj] = __builtin_amdgcn_mfma_f32_16x16x32_bf16(aL[fi], bH[fj], acc[fi][fj], 0, 0, 0);
                    }
            }
        }

        // ---- epilogue: tanh(kdec + x) * va, accumulate per-row partials ----
#pragma unroll
        for (int fj = 0; fj < 4; ++fj) {
            const int a = a0 + wc * 64 + fj * 16 + lr;   // == D col (lane&15)
            const float kd = kdec[(size_t)b * NA + a];
            const float vv = va[a];
#pragma unroll
            for (int fi = 0; fi < 4; ++fi)
#pragma unroll
                for (int r = 0; r < 4; ++r)
                    scp[fi][r] += tanh_fast(kd + acc[fi][fj][r]) * vv;
        }
    }

    // reduce across the 16 col-lanes of each group; rows: wr*64+fi*16+(lane>>4)*4+r
#pragma unroll
    for (int fi = 0; fi < 4; ++fi)
#pragma unroll
        for (int r = 0; r < 4; ++r) {
            float v = scp[fi][r];
            v += __shfl_xor(v, 1);
            v += __shfl_xor(v, 2);
            v += __shfl_xor(v, 4);
            v += __shfl_xor(v, 8);
            if (lr == 0)
                scLds[wc][wr * 64 + fi * 16 + (lane >> 4) * 4 + r] = v;
        }
    __syncthreads();
    if (t < BM)
        scores[(size_t)b * NS + s0 + t] = scLds[0][t] + scLds[1][t];
}

// ---------------- kernel 3: softmax over S (+ mask), zero ctx region ----------------
__global__ __launch_bounds__(256) void softmax_kernel(
    const float* __restrict__ scores, const int* __restrict__ mask,
    float* __restrict__ out /* d_out: [B*E ctx][B*S weights] */)
{
    __shared__ float red[8];
    const int b = blockIdx.x;
    const int t = threadIdx.x;
    float v[4];
    float mx = -INFINITY;
#pragma unroll
    for (int i = 0; i < 4; ++i) {
        const int s = t + i * 256;
        float x = scores[b * NS + s];
        if (mask[b * NS + s] == 0) x += -1e9f;   // src_mask uploaded as int32
        v[i] = x;
        mx = fmaxf(mx, x);
    }
    for (int off = 1; off < 64; off <<= 1) mx = fmaxf(mx, __shfl_xor(mx, off));
    const int wid = t >> 6;
    if ((t & 63) == 0) red[wid] = mx;
    __syncthreads();
    mx = fmaxf(fmaxf(red[0], red[1]), fmaxf(red[2], red[3]));
    float sum = 0.f;
#pragma unroll
    for (int i = 0; i < 4; ++i) { v[i] = expf(v[i] - mx); sum += v[i]; }
    for (int off = 1; off < 64; off <<= 1) sum += __shfl_xor(sum, off);
    if ((t & 63) == 0) red[4 + wid] = sum;
    __syncthreads();
    sum = red[4] + red[5] + red[6] + red[7];
    const float inv = 1.f / sum;
#pragma unroll
    for (int i = 0; i < 4; ++i) {
        const int s = t + i * 256;
        out[NB * NE + b * NS + s] = v[i] * inv;   // weights
        out[b * NE + s] = 0.f;                     // zero ctx[b,:] (E==S==1024)
    }
}

// ---------------- kernel 4: ctx[b,e] = sum_s w[b,s] * enc[b,s,e] ----------------
__global__ __launch_bounds__(256) void ctx_kernel(
    const float* __restrict__ enc, const float* __restrict__ w,
    float* __restrict__ ctx)
{
    __shared__ float wls[128];
    const int b  = blockIdx.x;
    const int ec = blockIdx.y;   // 0..3  (e chunk of 256)
    const int ss = blockIdx.z;   // 0..7  (s slice of 128)
    const int t  = threadIdx.x;
    if (t < 128) wls[t] = w[b * NS + ss * 128 + t];
    __syncthreads();
    const int e = ec * 256 + t;
    const float* p = enc + ((size_t)b * NS + ss * 128) * NE + e;
    float acc = 0.f;
#pragma unroll 4
    for (int s = 0; s < 128; ++s) acc += wls[s] * p[(size_t)s * NE];
    atomicAdd(&ctx[b * NE + e], acc);
}

extern "C" void kernel_launch(void* const* d_in, const int* in_sizes, int n_in,
                              void* d_out, int out_size, void* d_ws, size_t ws_size,
                              hipStream_t stream)
{
    const float* dec  = (const float*)d_in[0];
    const float* enc  = (const float*)d_in[1];
    const int*   mask = (const int*)d_in[2];     // bool -> int32 per harness
    const float* Wa   = (const float*)d_in[3];
    const float* Ua   = (const float*)d_in[4];
    const float* va   = (const float*)d_in[5];
    float* out = (float*)d_out;

    float* kdec            = (float*)d_ws;           // NB*NA fp32      (256 KB)
    float* scores          = kdec + NB * NA;         // NB*NS fp32      (256 KB)
    unsigned short* uatHi  = (unsigned short*)(scores + NB * NS);  // 2 MB
    unsigned short* uatLo  = uatHi + (size_t)NA * NE;              // 2 MB

    split_uat_kernel<<<dim3(NE / 32, NA / 32), 256, 0, stream>>>(Ua, uatHi, uatLo);
    kdec_kernel<<<dim3(NB, NA / 256), 256, 0, stream>>>(dec, Wa, kdec);
    scores_kernel<<<dim3(NS / BM, NB), 256, 0, stream>>>(enc, uatHi, uatLo, kdec, va, scores);
    softmax_kernel<<<dim3(NB), 256, 0, stream>>>(scores, mask, out);
    ctx_kernel<<<dim3(NB, NE / 256, NS / 128), 256, 0, stream>>>(enc, out + NB * NE, out);
}

// Round 5
// 1123.138 us; speedup vs baseline: 1.2190x; 1.2190x over previous
//
#include <hip/hip_runtime.h>
#include <hip/hip_bf16.h>
#include <math.h>

#define NB 64
#define NS 1024
#define NH 1024
#define NE 1024
#define NA 1024

#define BM 128
#define BN 128
#define BK 64
#define TILE_BYTES 16384   // 128 rows x 64 bf16 x 2B
#define TILE_ELEMS 8192

typedef __attribute__((ext_vector_type(8))) short bf16x8;
typedef __attribute__((ext_vector_type(4))) float f32x4;

__device__ __forceinline__ unsigned short f2bf(float x) {
    __hip_bfloat16 h = __float2bfloat16(x);
    return *reinterpret_cast<unsigned short*>(&h);
}
__device__ __forceinline__ float bf2f(unsigned short u) {
    __hip_bfloat16 h = *reinterpret_cast<__hip_bfloat16*>(&u);
    return __bfloat162float(h);
}
__device__ __forceinline__ float tanh_fast(float x) {
    float ax = fabsf(x);
    float e = __expf(-2.f * ax);
    float r = (1.f - e) / (1.f + e);
    return x < 0.f ? -r : r;
}
// XOR-swizzled byte offset into a [row][64 bf16] tile (row stride 128 B).
__device__ __forceinline__ int swz(int row, int colBf16) {
    return (row * 128 + colBf16 * 2) ^ ((row & 7) << 4);
}
__device__ __forceinline__ void gload_lds16(const void* g, void* l) {
    __builtin_amdgcn_global_load_lds(
        (const __attribute__((address_space(1))) unsigned int*)g,
        (__attribute__((address_space(3))) unsigned int*)l, 16, 0, 0);
}

// ======== PATH A: pre-split, pre-swizzled tiled workspace ========

// enc [b][s][e] f32 -> encHiT/encLoT tiles (b, sblk, eblk): 128(s) x 64(e) bf16, swizzled
__global__ __launch_bounds__(256) void split_enc_kernel(
    const float* __restrict__ enc,
    unsigned short* __restrict__ encHiT, unsigned short* __restrict__ encLoT)
{
    const int sblk = blockIdx.x;   // 0..7
    const int b    = blockIdx.y;   // 0..63
    const int t    = threadIdx.x;
    const float* src = enc + ((size_t)b * NS + sblk * 128) * NE;
    char* hiB = (char*)encHiT + (size_t)(b * 8 + sblk) * 16 * TILE_BYTES;
    char* loB = (char*)encLoT + (size_t)(b * 8 + sblk) * 16 * TILE_BYTES;
    for (int eblk = 0; eblk < 16; ++eblk) {
        char* hiT = hiB + (size_t)eblk * TILE_BYTES;
        char* loT = loB + (size_t)eblk * TILE_BYTES;
#pragma unroll
        for (int j = 0; j < 8; ++j) {
            const int flat = t + j * 256;      // 0..2047
            const int row  = flat >> 4;        // 0..127
            const int c4   = (flat & 15) * 4;  // 0..60 (floats)
            const float4 v = *reinterpret_cast<const float4*>(
                src + (size_t)row * NE + eblk * 64 + c4);
            ushort4 h, l;
            h.x = f2bf(v.x); l.x = f2bf(v.x - bf2f(h.x));
            h.y = f2bf(v.y); l.y = f2bf(v.y - bf2f(h.y));
            h.z = f2bf(v.z); l.z = f2bf(v.z - bf2f(h.z));
            h.w = f2bf(v.w); l.w = f2bf(v.w - bf2f(h.w));
            *reinterpret_cast<ushort4*>(hiT + swz(row, c4)) = h;
            *reinterpret_cast<ushort4*>(loT + swz(row, c4)) = l;
        }
    }
}

// Ua [e][a] f32 -> uatHiT/uatLoT tiles (ablk, eblk): 128(a) x 64(e) bf16, swizzled
__global__ __launch_bounds__(256) void split_uat_tiled_kernel(
    const float* __restrict__ Ua,
    unsigned short* __restrict__ uatHiT, unsigned short* __restrict__ uatLoT)
{
    __shared__ float ls[64][132];
    const int ablk = blockIdx.x;   // 0..7
    const int eblk = blockIdx.y;   // 0..15
    const int t = threadIdx.x;
    const int a0 = ablk * 128, e0 = eblk * 64;
#pragma unroll
    for (int j = 0; j < 8; ++j) {
        const int flat = t + j * 256;       // 0..2047
        const int e  = flat >> 5;           // 0..63
        const int c4 = (flat & 31) * 4;     // 0..124 (a, floats)
        *reinterpret_cast<float4*>(&ls[e][c4]) =
            *reinterpret_cast<const float4*>(Ua + (size_t)(e0 + e) * NA + a0 + c4);
    }
    __syncthreads();
    char* hiT = (char*)uatHiT + (size_t)(ablk * 16 + eblk) * TILE_BYTES;
    char* loT = (char*)uatLoT + (size_t)(ablk * 16 + eblk) * TILE_BYTES;
#pragma unroll
    for (int j = 0; j < 8; ++j) {
        const int flat = t + j * 256;       // 0..2047
        const int a  = flat >> 4;           // 0..127
        const int e4 = (flat & 15) * 4;     // 0..60
        const float x0 = ls[e4 + 0][a], x1 = ls[e4 + 1][a];
        const float x2 = ls[e4 + 2][a], x3 = ls[e4 + 3][a];
        ushort4 h, l;
        h.x = f2bf(x0); l.x = f2bf(x0 - bf2f(h.x));
        h.y = f2bf(x1); l.y = f2bf(x1 - bf2f(h.y));
        h.z = f2bf(x2); l.z = f2bf(x2 - bf2f(h.z));
        h.w = f2bf(x3); l.w = f2bf(x3 - bf2f(h.w));
        *reinterpret_cast<ushort4*>(hiT + swz(a, e4)) = h;
        *reinterpret_cast<ushort4*>(loT + swz(a, e4)) = l;
    }
}

// fused scores, 512 threads, dbuf LDS + gload_lds + depth-1 prefetch
__global__ __launch_bounds__(512, 1) void scores_mfma_kernel(
    const unsigned short* __restrict__ encHiT, const unsigned short* __restrict__ encLoT,
    const unsigned short* __restrict__ uatHiT, const unsigned short* __restrict__ uatLoT,
    const float* __restrict__ kdec, const float* __restrict__ va,
    float* __restrict__ scores)
{
    __shared__ __align__(16) char lds[2][65536];  // per buf: [aHi 16K][aLo 16K][bHi 16K][bLo 16K]
    __shared__ float scLds[4][BM];

    const int t    = threadIdx.x;
    const int sblk = blockIdx.x;
    const int b    = blockIdx.y;
    const int lane = t & 63;
    const int wid  = t >> 6;         // 0..7
    const int wr   = wid >> 2;       // 0..1  (64 s-rows)
    const int wc   = wid & 3;        // 0..3  (32 a-cols)
    const int lr   = lane & 15;
    const int lk   = (lane >> 4) * 8;

    const char* aHiB = (const char*)encHiT + (size_t)(b * 8 + sblk) * 16 * TILE_BYTES;
    const char* aLoB = (const char*)encLoT + (size_t)(b * 8 + sblk) * 16 * TILE_BYTES;
    const char* bHiB = (const char*)uatHiT;
    const char* bLoB = (const char*)uatLoT;

    auto STAGE = [&](int buf, int g) {
        const int ac = g >> 4, eblk = g & 15;
        const char* aHi = aHiB + (size_t)eblk * TILE_BYTES;
        const char* aLo = aLoB + (size_t)eblk * TILE_BYTES;
        const char* bHi = bHiB + (size_t)(ac * 16 + eblk) * TILE_BYTES;
        const char* bLo = bLoB + (size_t)(ac * 16 + eblk) * TILE_BYTES;
        char* dst = &lds[buf][0];
#pragma unroll
        for (int j = 0; j < 8; ++j) {
            const char* sb = (j < 2) ? aHi : (j < 4) ? aLo : (j < 6) ? bHi : bLo;
            const char* src = sb + ((j & 1) * 512 + t) * 16;     // per-lane source
            char* dstp = dst + (j * 512 + wid * 64) * 16;        // wave-uniform base
            gload_lds16(src, dstp);
        }
    };

    float scp[4][4];
#pragma unroll
    for (int i = 0; i < 4; ++i)
#pragma unroll
        for (int r = 0; r < 4; ++r) scp[i][r] = 0.f;

    STAGE(0, 0);
    __syncthreads();   // drains vmcnt before barrier

    int cur = 0;
    for (int ac = 0; ac < 8; ++ac) {
        f32x4 acc[4][2];
#pragma unroll
        for (int fi = 0; fi < 4; ++fi)
#pragma unroll
            for (int fj = 0; fj < 2; ++fj) acc[fi][fj] = (f32x4){0.f, 0.f, 0.f, 0.f};

        for (int e0i = 0; e0i < 16; ++e0i) {
            const int g = ac * 16 + e0i;
            if (g + 1 < 128) STAGE(cur ^ 1, g + 1);

            const char* L = &lds[cur][0];
#pragma unroll
            for (int ks = 0; ks < 2; ++ks) {
                const int col = ks * 32 + lk;
                bf16x8 aH[4], aL[4], bH[2], bL[2];
#pragma unroll
                for (int f = 0; f < 4; ++f) {
                    const int so = swz(wr * 64 + f * 16 + lr, col);
                    aH[f] = *reinterpret_cast<const bf16x8*>(L + so);
                    aL[f] = *reinterpret_cast<const bf16x8*>(L + 16384 + so);
                }
#pragma unroll
                for (int f = 0; f < 2; ++f) {
                    const int so = swz(wc * 32 + f * 16 + lr, col);
                    bH[f] = *reinterpret_cast<const bf16x8*>(L + 32768 + so);
                    bL[f] = *reinterpret_cast<const bf16x8*>(L + 49152 + so);
                }
#pragma unroll
                for (int fi = 0; fi < 4; ++fi)
#pragma unroll
                    for (int fj = 0; fj < 2; ++fj) {
                        acc[fi][fj] = __builtin_amdgcn_mfma_f32_16x16x32_bf16(aH[fi], bH[fj], acc[fi][fj], 0, 0, 0);
                        acc[fi][fj] = __builtin_amdgcn_mfma_f32_16x16x32_bf16(aH[fi], bL[fj], acc[fi][fj], 0, 0, 0);
                        acc[fi][fj] = __builtin_amdgcn_mfma_f32_16x16x32_bf16(aL[fi], bH[fj], acc[fi][fj], 0, 0, 0);
                    }
            }
            __syncthreads();   // implicit vmcnt(0)+lgkmcnt(0) drain: prefetch landed, reads done
            cur ^= 1;
        }

        // epilogue: tanh(kdec + x) * va
#pragma unroll
        for (int fj = 0; fj < 2; ++fj) {
            const int a = ac * BN + wc * 32 + fj * 16 + lr;
            const float kd = kdec[(size_t)b * NA + a];
            const float vv = va[a];
#pragma unroll
            for (int fi = 0; fi < 4; ++fi)
#pragma unroll
                for (int r = 0; r < 4; ++r)
                    scp[fi][r] += tanh_fast(kd + acc[fi][fj][r]) * vv;
        }
    }

#pragma unroll
    for (int fi = 0; fi < 4; ++fi)
#pragma unroll
        for (int r = 0; r < 4; ++r) {
            float v = scp[fi][r];
            v += __shfl_xor(v, 1);
            v += __shfl_xor(v, 2);
            v += __shfl_xor(v, 4);
            v += __shfl_xor(v, 8);
            if (lr == 0)
                scLds[wc][wr * 64 + fi * 16 + (lane >> 4) * 4 + r] = v;
        }
    __syncthreads();
    if (t < BM)
        scores[(size_t)b * NS + sblk * BM + t] =
            scLds[0][t] + scLds[1][t] + scLds[2][t] + scLds[3][t];
}

// ======== PATH B fallback (verified round-4 kernels) ========

__global__ __launch_bounds__(256) void split_uat_kernel(
    const float* __restrict__ Ua,
    unsigned short* __restrict__ uatHi, unsigned short* __restrict__ uatLo)
{
    __shared__ float tile[32][33];
    const int e0 = blockIdx.x * 32, a0 = blockIdx.y * 32;
    const int tx = threadIdx.x & 31, ty = threadIdx.x >> 5;
#pragma unroll
    for (int j = 0; j < 4; ++j)
        tile[ty + j * 8][tx] = Ua[(size_t)(e0 + ty + j * 8) * NA + a0 + tx];
    __syncthreads();
#pragma unroll
    for (int j = 0; j < 4; ++j) {
        const int a = a0 + ty + j * 8;
        const float x = tile[tx][ty + j * 8];
        const unsigned short h = f2bf(x);
        const unsigned short l = f2bf(x - bf2f(h));
        uatHi[(size_t)a * NE + e0 + tx] = h;
        uatLo[(size_t)a * NE + e0 + tx] = l;
    }
}

__global__ __launch_bounds__(256, 2) void scores_kernel(
    const float* __restrict__ enc,
    const unsigned short* __restrict__ uatHi, const unsigned short* __restrict__ uatLo,
    const float* __restrict__ kdec, const float* __restrict__ va,
    float* __restrict__ scores)
{
    __shared__ __align__(16) char aHi[BM * BK * 2];
    __shared__ __align__(16) char aLo[BM * BK * 2];
    __shared__ __align__(16) char bHi[BN * BK * 2];
    __shared__ __align__(16) char bLo[BN * BK * 2];
    __shared__ float scLds[2][BM];

    const int t    = threadIdx.x;
    const int b    = blockIdx.y;
    const int s0   = blockIdx.x * BM;
    const int lane = t & 63;
    const int wid  = t >> 6;
    const int wr   = wid >> 1;
    const int wc   = wid & 1;
    const int lr   = lane & 15;
    const int lk   = (lane >> 4) * 8;

    const float* encB = enc + ((size_t)b * NS + s0) * NE;

    float scp[4][4];
#pragma unroll
    for (int i = 0; i < 4; ++i)
#pragma unroll
        for (int r = 0; r < 4; ++r) scp[i][r] = 0.f;

    for (int ac = 0; ac < NA / BN; ++ac) {
        const int a0 = ac * BN;
        f32x4 acc[4][4];
#pragma unroll
        for (int fi = 0; fi < 4; ++fi)
#pragma unroll
            for (int fj = 0; fj < 4; ++fj) acc[fi][fj] = (f32x4){0.f, 0.f, 0.f, 0.f};

        for (int e0 = 0; e0 < NE; e0 += BK) {
            __syncthreads();
#pragma unroll
            for (int it = 0; it < 8; ++it) {
                int flat = t + it * 256;
                int row  = flat >> 4;
                int c4   = (flat & 15) * 4;
                const float4 v = *reinterpret_cast<const float4*>(
                    encB + (size_t)row * NE + e0 + c4);
                ushort4 h, l;
                h.x = f2bf(v.x); l.x = f2bf(v.x - bf2f(h.x));
                h.y = f2bf(v.y); l.y = f2bf(v.y - bf2f(h.y));
                h.z = f2bf(v.z); l.z = f2bf(v.z - bf2f(h.z));
                h.w = f2bf(v.w); l.w = f2bf(v.w - bf2f(h.w));
                *reinterpret_cast<ushort4*>(aHi + swz(row, c4)) = h;
                *reinterpret_cast<ushort4*>(aLo + swz(row, c4)) = l;
            }
#pragma unroll
            for (int it = 0; it < 4; ++it) {
                int flat = t + it * 256;
                int row  = flat >> 3;
                int c8   = (flat & 7) * 8;
                const size_t g = (size_t)(a0 + row) * NE + e0 + c8;
                *reinterpret_cast<int4*>(bHi + swz(row, c8)) =
                    *reinterpret_cast<const int4*>(uatHi + g);
                *reinterpret_cast<int4*>(bLo + swz(row, c8)) =
                    *reinterpret_cast<const int4*>(uatLo + g);
            }
            __syncthreads();

#pragma unroll
            for (int ks = 0; ks < BK; ks += 32) {
                bf16x8 aH[4], aL[4], bH[4], bL[4];
#pragma unroll
                for (int f = 0; f < 4; ++f) {
                    aH[f] = *reinterpret_cast<const bf16x8*>(aHi + swz(wr * 64 + f * 16 + lr, ks + lk));
                    aL[f] = *reinterpret_cast<const bf16x8*>(aLo + swz(wr * 64 + f * 16 + lr, ks + lk));
                    bH[f] = *reinterpret_cast<const bf16x8*>(bHi + swz(wc * 64 + f * 16 + lr, ks + lk));
                    bL[f] = *reinterpret_cast<const bf16x8*>(bLo + swz(wc * 64 + f * 16 + lr, ks + lk));
                }
#pragma unroll
                for (int fi = 0; fi < 4; ++fi)
#pragma unroll
                    for (int fj = 0; fj < 4; ++fj) {
                        acc[fi][fj] = __builtin_amdgcn_mfma_f32_16x16x32_bf16(aH[fi], bH[fj], acc[fi][fj], 0, 0, 0);
                        acc[fi][fj] = __builtin_amdgcn_mfma_f32_16x16x32_bf16(aH[fi], bL[fj], acc[fi][fj], 0, 0, 0);
                        acc[fi][fj] = __builtin_amdgcn_mfma_f32_16x16x32_bf16(aL[fi], bH[fj], acc[fi][fj], 0, 0, 0);
                    }
            }
        }
#pragma unroll
        for (int fj = 0; fj < 4; ++fj) {
            const int a = a0 + wc * 64 + fj * 16 + lr;
            const float kd = kdec[(size_t)b * NA + a];
            const float vv = va[a];
#pragma unroll
            for (int fi = 0; fi < 4; ++fi)
#pragma unroll
                for (int r = 0; r < 4; ++r)
                    scp[fi][r] += tanh_fast(kd + acc[fi][fj][r]) * vv;
        }
    }
#pragma unroll
    for (int fi = 0; fi < 4; ++fi)
#pragma unroll
        for (int r = 0; r < 4; ++r) {
            float v = scp[fi][r];
            v += __shfl_xor(v, 1);
            v += __shfl_xor(v, 2);
            v += __shfl_xor(v, 4);
            v += __shfl_xor(v, 8);
            if (lr == 0)
                scLds[wc][wr * 64 + fi * 16 + (lane >> 4) * 4 + r] = v;
        }
    __syncthreads();
    if (t < BM)
        scores[(size_t)b * NS + s0 + t] = scLds[0][t] + scLds[1][t];
}

// ======== shared kernels ========

__global__ __launch_bounds__(256) void kdec_kernel(
    const float* __restrict__ dec, const float* __restrict__ Wa,
    float* __restrict__ kdec)
{
    __shared__ float dls[NH];
    const int b = blockIdx.x;
    const int a = blockIdx.y * 256 + threadIdx.x;
    for (int i = threadIdx.x; i < NH; i += 256) dls[i] = dec[b * NH + i];
    __syncthreads();
    float acc = 0.f;
#pragma unroll 8
    for (int h = 0; h < NH; ++h) acc += dls[h] * Wa[(size_t)h * NA + a];
    kdec[b * NA + a] = acc;
}

__global__ __launch_bounds__(256) void softmax_kernel(
    const float* __restrict__ scores, const int* __restrict__ mask,
    float* __restrict__ out)
{
    __shared__ float red[8];
    const int b = blockIdx.x;
    const int t = threadIdx.x;
    float v[4];
    float mx = -INFINITY;
#pragma unroll
    for (int i = 0; i < 4; ++i) {
        const int s = t + i * 256;
        float x = scores[b * NS + s];
        if (mask[b * NS + s] == 0) x += -1e9f;
        v[i] = x;
        mx = fmaxf(mx, x);
    }
    for (int off = 1; off < 64; off <<= 1) mx = fmaxf(mx, __shfl_xor(mx, off));
    const int wid = t >> 6;
    if ((t & 63) == 0) red[wid] = mx;
    __syncthreads();
    mx = fmaxf(fmaxf(red[0], red[1]), fmaxf(red[2], red[3]));
    float sum = 0.f;
#pragma unroll
    for (int i = 0; i < 4; ++i) { v[i] = expf(v[i] - mx); sum += v[i]; }
    for (int off = 1; off < 64; off <<= 1) sum += __shfl_xor(sum, off);
    if ((t & 63) == 0) red[4 + wid] = sum;
    __syncthreads();
    sum = red[4] + red[5] + red[6] + red[7];
    const float inv = 1.f / sum;
#pragma unroll
    for (int i = 0; i < 4; ++i) {
        const int s = t + i * 256;
        out[NB * NE + b * NS + s] = v[i] * inv;
        out[b * NE + s] = 0.f;
    }
}

__global__ __launch_bounds__(256) void ctx_kernel(
    const float* __restrict__ enc, const float* __restrict__ w,
    float* __restrict__ ctx)
{
    __shared__ float wls[128];
    const int b  = blockIdx.x;
    const int ec = blockIdx.y;
    const int ss = blockIdx.z;
    const int t  = threadIdx.x;
    if (t < 128) wls[t] = w[b * NS + ss * 128 + t];
    __syncthreads();
    const int e = ec * 256 + t;
    const float* p = enc + ((size_t)b * NS + ss * 128) * NE + e;
    float acc = 0.f;
#pragma unroll 4
    for (int s = 0; s < 128; ++s) acc += wls[s] * p[(size_t)s * NE];
    atomicAdd(&ctx[b * NE + e], acc);
}

extern "C" void kernel_launch(void* const* d_in, const int* in_sizes, int n_in,
                              void* d_out, int out_size, void* d_ws, size_t ws_size,
                              hipStream_t stream)
{
    const float* dec  = (const float*)d_in[0];
    const float* enc  = (const float*)d_in[1];
    const int*   mask = (const int*)d_in[2];
    const float* Wa   = (const float*)d_in[3];
    const float* Ua   = (const float*)d_in[4];
    const float* va   = (const float*)d_in[5];
    float* out = (float*)d_out;

    float* kdec   = (float*)d_ws;              // 256 KB
    float* scores = kdec + NB * NA;            // 256 KB
    unsigned short* w0 = (unsigned short*)(scores + NB * NS);

    const size_t uatElems = (size_t)NA * NE;        // 1M elems -> 2 MB each
    const size_t encElems = (size_t)NB * NS * NE;   // 64M elems -> 128 MB each
    const size_t needA = 512ull * 1024 + 2 * uatElems * 2 + 2 * encElems * 2;

    kdec_kernel<<<dim3(NB, NA / 256), 256, 0, stream>>>(dec, Wa, kdec);

    if (ws_size >= needA) {
        unsigned short* uatHiT = w0;
        unsigned short* uatLoT = uatHiT + uatElems;
        unsigned short* encHiT = uatLoT + uatElems;
        unsigned short* encLoT = encHiT + encElems;
        split_uat_tiled_kernel<<<dim3(8, 16), 256, 0, stream>>>(Ua, uatHiT, uatLoT);
        split_enc_kernel<<<dim3(8, NB), 256, 0, stream>>>(enc, encHiT, encLoT);
        scores_mfma_kernel<<<dim3(8, NB), 512, 0, stream>>>(
            encHiT, encLoT, uatHiT, uatLoT, kdec, va, scores);
    } else {
        unsigned short* uatHi = w0;
        unsigned short* uatLo = uatHi + uatElems;
        split_uat_kernel<<<dim3(NE / 32, NA / 32), 256, 0, stream>>>(Ua, uatHi, uatLo);
        scores_kernel<<<dim3(NS / BM, NB), 256, 0, stream>>>(enc, uatHi, uatLo, kdec, va, scores);
    }

    softmax_kernel<<<dim3(NB), 256, 0, stream>>>(scores, mask, out);
    ctx_kernel<<<dim3(NB, NE / 256, NS / 128), 256, 0, stream>>>(enc, out + NB * NE, out);
}

// Round 6
// 1097.433 us; speedup vs baseline: 1.2476x; 1.0234x over previous
//
#include <hip/hip_runtime.h>
#include <hip/hip_bf16.h>
#include <math.h>

#define NB 64
#define NS 1024
#define NH 1024
#define NE 1024
#define NA 1024

// scores geometry: block = 128 s x 256 a, BK=32, 8 waves (2s x 4a), wave-out 64x64
#define A_TILE 8192        // 128 rows x 32 bf16 x 2B
#define B_TILE 16384       // 256 rows x 32 bf16 x 2B
#define BUF_BYTES 49152    // [aHi 8K][aLo 8K][bHi 16K][bLo 16K]
#define NT 128             // 4 a-chunks x 32 e-tiles

typedef __attribute__((ext_vector_type(8))) short bf16x8;
typedef __attribute__((ext_vector_type(8))) unsigned short ushort8_t;
typedef __attribute__((ext_vector_type(4))) float f32x4;

__device__ __forceinline__ unsigned short f2bf(float x) {
    __hip_bfloat16 h = __float2bfloat16(x);
    return *reinterpret_cast<unsigned short*>(&h);
}
__device__ __forceinline__ float bf2f(unsigned short u) {
    __hip_bfloat16 h = *reinterpret_cast<__hip_bfloat16*>(&u);
    return __bfloat162float(h);
}
__device__ __forceinline__ float tanh_fast(float x) {
    float ax = fabsf(x);
    float e = __expf(-2.f * ax);
    float r = (1.f - e) / (1.f + e);
    return x < 0.f ? -r : r;
}
// 64-B rows (32 bf16): XOR 16B-slot bits [5:4] with (row>>1)&3.
// 16-row x 4-kgroup b128 reads spread over all 32 banks at exactly 2-way (free).
__device__ __forceinline__ int swz32(int row, int bcol) {
    return row * 64 + (bcol ^ (((row >> 1) & 3) << 4));
}
__device__ __forceinline__ void gload_lds16(const void* g, void* l) {
    __builtin_amdgcn_global_load_lds(
        (const __attribute__((address_space(1))) unsigned int*)g,
        (__attribute__((address_space(3))) unsigned int*)l, 16, 0, 0);
}

// ---- split enc -> pre-swizzled 128x32 bf16 hi/lo tiles, (b,sblk) x 32 et ----
__global__ __launch_bounds__(256) void split_enc_kernel(
    const float* __restrict__ enc,
    unsigned short* __restrict__ encHiT, unsigned short* __restrict__ encLoT)
{
    const int sblk = blockIdx.x;   // 0..7
    const int b    = blockIdx.y;   // 0..63
    const int t    = threadIdx.x;  // 0..255 (one float4 per row-pass)
    const float* src = enc + ((size_t)b * NS + sblk * 128) * NE;
    char* hiB = (char*)encHiT + (size_t)(b * 8 + sblk) * 32 * A_TILE;
    char* loB = (char*)encLoT + (size_t)(b * 8 + sblk) * 32 * A_TILE;
    const int et   = t >> 3;
    const int bcol = (t & 7) * 8;
    for (int row = 0; row < 128; ++row) {
        const float4 v = *reinterpret_cast<const float4*>(src + (size_t)row * NE + t * 4);
        ushort4 h, l;
        h.x = f2bf(v.x); l.x = f2bf(v.x - bf2f(h.x));
        h.y = f2bf(v.y); l.y = f2bf(v.y - bf2f(h.y));
        h.z = f2bf(v.z); l.z = f2bf(v.z - bf2f(h.z));
        h.w = f2bf(v.w); l.w = f2bf(v.w - bf2f(h.w));
        const int off = (size_t)et * A_TILE + swz32(row, bcol);
        *reinterpret_cast<ushort4*>(hiB + off) = h;
        *reinterpret_cast<ushort4*>(loB + off) = l;
    }
}

// ---- split Ua^T -> pre-swizzled 256x32 bf16 hi/lo tiles, (ac) x 32 et ----
__global__ __launch_bounds__(256) void split_uat_kernel(
    const float* __restrict__ Ua,
    unsigned short* __restrict__ uatHiT, unsigned short* __restrict__ uatLoT)
{
    __shared__ float ls[32][257];
    const int ac = blockIdx.x;     // 0..3   (a-chunk of 256)
    const int eb = blockIdx.y;     // 0..31  (== et)
    const int t  = threadIdx.x;
    const int a0 = ac * 256, e0 = eb * 32;
#pragma unroll
    for (int p = 0; p < 8; ++p) {
        const int flat = p * 256 + t;      // 2048 float4: e(32) x q(64)
        const int e = flat >> 6, q = flat & 63;
        *reinterpret_cast<float4*>(&ls[e][q * 4]) =
            *reinterpret_cast<const float4*>(Ua + (size_t)(e0 + e) * NA + a0 + q * 4);
    }
    __syncthreads();
    char* hiT = (char*)uatHiT + (size_t)(ac * 32 + eb) * B_TILE;
    char* loT = (char*)uatLoT + (size_t)(ac * 32 + eb) * B_TILE;
#pragma unroll
    for (int p = 0; p < 4; ++p) {
        const int flat = p * 256 + t;      // 1024: a(256) x octet(4)
        const int a = flat >> 2, o = flat & 3;
        ushort8_t h8, l8;
#pragma unroll
        for (int j = 0; j < 8; ++j) {
            const float x = ls[o * 8 + j][a];
            const unsigned short hh = f2bf(x);
            h8[j] = hh;
            l8[j] = f2bf(x - bf2f(hh));
        }
        const int off = swz32(a, o * 16);
        *reinterpret_cast<int4*>(hiT + off) = *reinterpret_cast<int4*>(&h8);
        *reinterpret_cast<int4*>(loT + off) = *reinterpret_cast<int4*>(&l8);
    }
}

// ---- k_dec = dec @ W_a ----
__global__ __launch_bounds__(256) void kdec_kernel(
    const float* __restrict__ dec, const float* __restrict__ Wa,
    float* __restrict__ kdec)
{
    __shared__ float dls[NH];
    const int b = blockIdx.x;
    const int a = blockIdx.y * 256 + threadIdx.x;
    for (int i = threadIdx.x; i < NH; i += 256) dls[i] = dec[b * NH + i];
    __syncthreads();
    float acc = 0.f;
#pragma unroll 8
    for (int h = 0; h < NH; ++h) acc += dls[h] * Wa[(size_t)h * NA + a];
    kdec[b * NA + a] = acc;
}

// ---- fused scores: split-bf16 MFMA, 3-buffer counted-vmcnt pipeline ----
__global__ __launch_bounds__(512, 2) void scores_mfma2_kernel(
    const unsigned short* __restrict__ encHiT, const unsigned short* __restrict__ encLoT,
    const unsigned short* __restrict__ uatHiT, const unsigned short* __restrict__ uatLoT,
    const float* __restrict__ kdec, const float* __restrict__ va,
    float* __restrict__ scores)
{
    __shared__ __align__(16) char lds[3 * BUF_BYTES];   // 147456 B
    __shared__ float scLds[4][128];

    const int t    = threadIdx.x;
    const int sblk = blockIdx.x;
    const int b    = blockIdx.y;
    const int lane = t & 63;
    const int wid  = t >> 6;        // 0..7
    const int wr   = wid >> 2;      // 0..1 (64 s-rows)
    const int wc   = wid & 3;       // 0..3 (64 a-cols)
    const int lrow = lane & 15;
    const int kb   = (lane >> 4) * 16;   // byte col of k-octet

    const char* aHiB = (const char*)encHiT + (size_t)(b * 8 + sblk) * 32 * A_TILE;
    const char* aLoB = (const char*)encLoT + (size_t)(b * 8 + sblk) * 32 * A_TILE;
    const char* bHiB = (const char*)uatHiT;
    const char* bLoB = (const char*)uatLoT;

    // swizzle-invariant LDS read offsets (tile-independent)
    int aOff[4], bOff[4];
#pragma unroll
    for (int f = 0; f < 4; ++f) {
        aOff[f] = swz32(wr * 64 + f * 16 + lrow, kb);
        bOff[f] = swz32(wc * 64 + f * 16 + lrow, kb);
    }

    // preload kdec/va for all 4 chunks (keeps VMEM out of the vmcnt protocol)
    float kd[4][4], vv[4][4];
#pragma unroll
    for (int ac = 0; ac < 4; ++ac)
#pragma unroll
        for (int fj = 0; fj < 4; ++fj) {
            const int a = ac * 256 + wc * 64 + fj * 16 + lrow;
            kd[ac][fj] = kdec[(size_t)b * NA + a];
            vv[ac][fj] = va[a];
        }

    auto STAGE = [&](int g, int buf) {
        const int ac2 = g >> 5, et2 = g & 31;
        const char* aHi = aHiB + (size_t)et2 * A_TILE;
        const char* aLo = aLoB + (size_t)et2 * A_TILE;
        const char* bHi = bHiB + (size_t)(ac2 * 32 + et2) * B_TILE;
        const char* bLo = bLoB + (size_t)(ac2 * 32 + et2) * B_TILE;
        char* dst = lds + buf * BUF_BYTES;
        const int so = t * 16;          // per-lane source offset
        const int wo = wid * 1024;      // wave-uniform LDS base offset
        gload_lds16(aHi + so,        dst + 0 * 8192 + wo);
        gload_lds16(aLo + so,        dst + 1 * 8192 + wo);
        gload_lds16(bHi + so,        dst + 2 * 8192 + wo);
        gload_lds16(bHi + 8192 + so, dst + 3 * 8192 + wo);
        gload_lds16(bLo + so,        dst + 4 * 8192 + wo);
        gload_lds16(bLo + 8192 + so, dst + 5 * 8192 + wo);
    };

    float scp[4][4];
#pragma unroll
    for (int i = 0; i < 4; ++i)
#pragma unroll
        for (int r = 0; r < 4; ++r) scp[i][r] = 0.f;

    // prologue: stage tiles 0,1 (no drain; loop's vmcnt(12) covers tile 0)
    STAGE(0, 0);
    STAGE(1, 1);

    int cur = 0;
#pragma unroll
    for (int ac = 0; ac < 4; ++ac) {
        f32x4 acc[4][4];
#pragma unroll
        for (int fi = 0; fi < 4; ++fi)
#pragma unroll
            for (int fj = 0; fj < 4; ++fj) acc[fi][fj] = (f32x4){0.f, 0.f, 0.f, 0.f};

        for (int et = 0; et < 32; ++et) {
            const int g = ac * 32 + et;
            if (g + 2 < NT) {
                int nb = cur + 2; if (nb >= 3) nb -= 3;
                STAGE(g + 2, nb);
                // tile g done when <=12 outstanding (t+1, t+2 in flight, in-order retire)
                asm volatile("s_waitcnt vmcnt(12)" ::: "memory");
            } else if (g + 1 < NT) {
                asm volatile("s_waitcnt vmcnt(6)" ::: "memory");
            } else {
                asm volatile("s_waitcnt vmcnt(0)" ::: "memory");
            }
            asm volatile("s_barrier" ::: "memory");   // buf[cur] ready for all waves

            const char* L = lds + cur * BUF_BYTES;
            bf16x8 aH[4], aL[4], bH[4], bL[4];
#pragma unroll
            for (int f = 0; f < 4; ++f) {
                aH[f] = *reinterpret_cast<const bf16x8*>(L + aOff[f]);
                aL[f] = *reinterpret_cast<const bf16x8*>(L + A_TILE + aOff[f]);
                bH[f] = *reinterpret_cast<const bf16x8*>(L + 2 * A_TILE + bOff[f]);
                bL[f] = *reinterpret_cast<const bf16x8*>(L + 2 * A_TILE + B_TILE + bOff[f]);
            }
            __builtin_amdgcn_s_setprio(1);
#pragma unroll
            for (int fi = 0; fi < 4; ++fi)
#pragma unroll
                for (int fj = 0; fj < 4; ++fj) {
                    acc[fi][fj] = __builtin_amdgcn_mfma_f32_16x16x32_bf16(aH[fi], bH[fj], acc[fi][fj], 0, 0, 0);
                    acc[fi][fj] = __builtin_amdgcn_mfma_f32_16x16x32_bf16(aH[fi], bL[fj], acc[fi][fj], 0, 0, 0);
                    acc[fi][fj] = __builtin_amdgcn_mfma_f32_16x16x32_bf16(aL[fi], bH[fj], acc[fi][fj], 0, 0, 0);
                }
            __builtin_amdgcn_s_setprio(0);
            // pin reads+waits above the end barrier (rule #18), then release buffer
            __builtin_amdgcn_sched_barrier(0);
            asm volatile("s_waitcnt lgkmcnt(0)" ::: "memory");
            asm volatile("s_barrier" ::: "memory");   // all waves done reading buf[cur]
            cur += 1; if (cur >= 3) cur -= 3;
        }

        // epilogue: tanh(kdec + x) * va  (static indices only)
#pragma unroll
        for (int fj = 0; fj < 4; ++fj)
#pragma unroll
            for (int fi = 0; fi < 4; ++fi)
#pragma unroll
                for (int r = 0; r < 4; ++r)
                    scp[fi][r] += tanh_fast(kd[ac][fj] + acc[fi][fj][r]) * vv[ac][fj];
    }

    // reduce over the 16 col-lanes, then across the 4 a-wave-columns via LDS
#pragma unroll
    for (int fi = 0; fi < 4; ++fi)
#pragma unroll
        for (int r = 0; r < 4; ++r) {
            float v = scp[fi][r];
            v += __shfl_xor(v, 1);
            v += __shfl_xor(v, 2);
            v += __shfl_xor(v, 4);
            v += __shfl_xor(v, 8);
            if (lrow == 0)
                scLds[wc][wr * 64 + fi * 16 + (lane >> 4) * 4 + r] = v;
        }
    __syncthreads();
    if (t < 128)
        scores[(size_t)b * NS + sblk * 128 + t] =
            scLds[0][t] + scLds[1][t] + scLds[2][t] + scLds[3][t];
}

// ---- softmax over S (+ mask), zero ctx region ----
__global__ __launch_bounds__(256) void softmax_kernel(
    const float* __restrict__ scores, const int* __restrict__ mask,
    float* __restrict__ out)
{
    __shared__ float red[8];
    const int b = blockIdx.x;
    const int t = threadIdx.x;
    float v[4];
    float mx = -INFINITY;
#pragma unroll
    for (int i = 0; i < 4; ++i) {
        const int s = t + i * 256;
        float x = scores[b * NS + s];
        if (mask[b * NS + s] == 0) x += -1e9f;
        v[i] = x;
        mx = fmaxf(mx, x);
    }
    for (int off = 1; off < 64; off <<= 1) mx = fmaxf(mx, __shfl_xor(mx, off));
    const int wid = t >> 6;
    if ((t & 63) == 0) red[wid] = mx;
    __syncthreads();
    mx = fmaxf(fmaxf(red[0], red[1]), fmaxf(red[2], red[3]));
    float sum = 0.f;
#pragma unroll
    for (int i = 0; i < 4; ++i) { v[i] = expf(v[i] - mx); sum += v[i]; }
    for (int off = 1; off < 64; off <<= 1) sum += __shfl_xor(sum, off);
    if ((t & 63) == 0) red[4 + wid] = sum;
    __syncthreads();
    sum = red[4] + red[5] + red[6] + red[7];
    const float inv = 1.f / sum;
#pragma unroll
    for (int i = 0; i < 4; ++i) {
        const int s = t + i * 256;
        out[NB * NE + b * NS + s] = v[i] * inv;   // weights
        out[b * NE + s] = 0.f;                     // zero ctx (E==S==1024)
    }
}

// ---- ctx[b,e] = sum_s w[b,s] * enc[b,s,e] ----
__global__ __launch_bounds__(256) void ctx_kernel(
    const float* __restrict__ enc, const float* __restrict__ w,
    float* __restrict__ ctx)
{
    __shared__ float wls[128];
    const int b  = blockIdx.x;
    const int ec = blockIdx.y;
    const int ss = blockIdx.z;
    const int t  = threadIdx.x;
    if (t < 128) wls[t] = w[b * NS + ss * 128 + t];
    __syncthreads();
    const int e = ec * 256 + t;
    const float* p = enc + ((size_t)b * NS + ss * 128) * NE + e;
    float acc = 0.f;
#pragma unroll 4
    for (int s = 0; s < 128; ++s) acc += wls[s] * p[(size_t)s * NE];
    atomicAdd(&ctx[b * NE + e], acc);
}

extern "C" void kernel_launch(void* const* d_in, const int* in_sizes, int n_in,
                              void* d_out, int out_size, void* d_ws, size_t ws_size,
                              hipStream_t stream)
{
    const float* dec  = (const float*)d_in[0];
    const float* enc  = (const float*)d_in[1];
    const int*   mask = (const int*)d_in[2];     // bool -> int32 per harness
    const float* Wa   = (const float*)d_in[3];
    const float* Ua   = (const float*)d_in[4];
    const float* va   = (const float*)d_in[5];
    float* out = (float*)d_out;

    float* kdec   = (float*)d_ws;              // 256 KB
    float* scores = kdec + NB * NA;            // 256 KB
    unsigned short* uatHiT = (unsigned short*)(scores + NB * NS);   // 2 MB
    unsigned short* uatLoT = uatHiT + (size_t)NA * NE;              // 2 MB
    unsigned short* encHiT = uatLoT + (size_t)NA * NE;              // 128 MB
    unsigned short* encLoT = encHiT + (size_t)NB * NS * NE;         // 128 MB

    kdec_kernel<<<dim3(NB, NA / 256), 256, 0, stream>>>(dec, Wa, kdec);
    split_uat_kernel<<<dim3(4, 32), 256, 0, stream>>>(Ua, uatHiT, uatLoT);
    split_enc_kernel<<<dim3(8, NB), 256, 0, stream>>>(enc, encHiT, encLoT);
    scores_mfma2_kernel<<<dim3(8, NB), 512, 0, stream>>>(
        encHiT, encLoT, uatHiT, uatLoT, kdec, va, scores);
    softmax_kernel<<<dim3(NB), 256, 0, stream>>>(scores, mask, out);
    ctx_kernel<<<dim3(NB, NE / 256, NS / 128), 256, 0, stream>>>(enc, out + NB * NE, out);
}